// Round 1
// baseline (58.433 us; speedup 1.0000x reference)
//
#include <hip/hip_runtime.h>

// GaussianMask: K[b,c,k,h,w] = exp(-(Xnbr - Xctr)^2 / (2*bw^2)), bw=1
// X: (4,3,512,512) fp32. Out: (4,3,24,512,512) fp32. Zero padding, center tap skipped.

#define HH 512
#define WW 512
#define NPLANES 12   // B*C = 4*3
#define NK 24

__global__ __launch_bounds__(256) void gauss_mask_kernel(
    const float* __restrict__ X, float* __restrict__ out)
{
    // one thread handles 4 consecutive w positions (one float4)
    const int tid = blockIdx.x * blockDim.x + threadIdx.x;
    // quads per plane = 512 * 128 = 65536
    const int p   = tid >> 16;
    const int rem = tid & 65535;
    const int h   = rem >> 7;          // row
    const int w0  = (rem & 127) << 2;  // starting col (multiple of 4)

    const float* Xp = X + (size_t)p * (HH * WW);

    // center values
    const float4 xi4 = *reinterpret_cast<const float4*>(Xp + (size_t)h * WW + w0);
    float xiv[4] = {xi4.x, xi4.y, xi4.z, xi4.w};

    // 5x8 neighborhood window in registers, zero-filled out of bounds
    float rows[5][8];
    #pragma unroll
    for (int dr = 0; dr < 5; ++dr) {
        const int hh = h + dr - 2;
        const bool rok = (hh >= 0) && (hh < HH);
        const float* rptr = Xp + (size_t)hh * WW;
        #pragma unroll
        for (int j = 0; j < 8; ++j) {
            const int ww = w0 + j - 2;
            rows[dr][j] = (rok && ww >= 0 && ww < WW) ? rptr[ww] : 0.0f;
        }
    }

    // exp(-d^2 * 0.5) = exp2(d^2 * (-0.5 * log2(e)))
    const float c = -0.5f * 1.44269504088896340736f;

    float* outp = out + (size_t)p * NK * HH * WW + (size_t)h * WW + w0;

    #pragma unroll
    for (int k = 0; k < NK; ++k) {
        const int idx = (k < 12) ? k : k + 1;   // skip center tap (2,2)
        const int dr = idx / 5;
        const int dc = idx % 5;
        float4 v;
        float* vv = &v.x;
        #pragma unroll
        for (int i = 0; i < 4; ++i) {
            const float d = rows[dr][dc + i] - xiv[i];
            vv[i] = exp2f(d * d * c);
        }
        *reinterpret_cast<float4*>(outp + (size_t)k * (HH * WW)) = v;
    }
}

extern "C" void kernel_launch(void* const* d_in, const int* in_sizes, int n_in,
                              void* d_out, int out_size, void* d_ws, size_t ws_size,
                              hipStream_t stream) {
    const float* X = (const float*)d_in[0];
    float* out = (float*)d_out;

    // total quads = 12 planes * 512 rows * 128 quads/row = 786432 threads
    const int total = NPLANES * HH * (WW / 4);
    const int block = 256;
    const int grid = total / block;  // 3072
    gauss_mask_kernel<<<grid, block, 0, stream>>>(X, out);
}

// Round 3
// 55.677 us; speedup vs baseline: 1.0495x; 1.0495x over previous
//
#include <hip/hip_runtime.h>

// GaussianMask: K[b,c,k,h,w] = exp(-(Xnbr - Xctr)^2 / 2), bw=1
// X: (4,3,512,512) fp32. Out: (4,3,24,512,512) fp32. Zero padding, center tap skipped.
// Write-BW-bound: 302 MB out vs 12.6 MB in. This revision: nontemporal stores
// via native clang vector type (HIP_vector_type is rejected by the builtin).

#define HH 512
#define WW 512
#define NPLANES 12   // B*C = 4*3
#define NK 24

typedef float f32x4 __attribute__((ext_vector_type(4)));

extern "C" __device__ float __builtin_amdgcn_exp2f(float);

__global__ __launch_bounds__(256) void gauss_mask_kernel(
    const float* __restrict__ X, float* __restrict__ out)
{
    // one thread handles 4 consecutive w positions (one float4)
    const int tid = blockIdx.x * blockDim.x + threadIdx.x;
    // quads per plane = 512 * 128 = 65536
    const int p   = tid >> 16;
    const int rem = tid & 65535;
    const int h   = rem >> 7;          // row
    const int w0  = (rem & 127) << 2;  // starting col (multiple of 4)

    const float* Xp = X + (size_t)p * (HH * WW);

    // center values
    const f32x4 xi4 = *reinterpret_cast<const f32x4*>(Xp + (size_t)h * WW + w0);
    float xiv[4] = {xi4.x, xi4.y, xi4.z, xi4.w};

    // 5x8 neighborhood window in registers, zero-filled out of bounds
    float rows[5][8];
    #pragma unroll
    for (int dr = 0; dr < 5; ++dr) {
        const int hh = h + dr - 2;
        const bool rok = (hh >= 0) && (hh < HH);
        const float* rptr = Xp + (size_t)hh * WW;
        #pragma unroll
        for (int j = 0; j < 8; ++j) {
            const int ww = w0 + j - 2;
            rows[dr][j] = (rok && ww >= 0 && ww < WW) ? rptr[ww] : 0.0f;
        }
    }

    // exp(-d^2 * 0.5) = exp2(d^2 * (-0.5 * log2(e)))
    const float c = -0.5f * 1.44269504088896340736f;

    float* outp = out + (size_t)p * NK * HH * WW + (size_t)h * WW + w0;

    #pragma unroll
    for (int k = 0; k < NK; ++k) {
        const int idx = (k < 12) ? k : k + 1;   // skip center tap (2,2)
        const int dr = idx / 5;
        const int dc = idx % 5;
        f32x4 v;
        #pragma unroll
        for (int i = 0; i < 4; ++i) {
            const float d = rows[dr][dc + i] - xiv[i];
            v[i] = __builtin_amdgcn_exp2f(d * d * c);
        }
        // streaming store: output is write-once, never re-read -> bypass L2 allocate
        __builtin_nontemporal_store(v, reinterpret_cast<f32x4*>(outp + (size_t)k * (HH * WW)));
    }
}

extern "C" void kernel_launch(void* const* d_in, const int* in_sizes, int n_in,
                              void* d_out, int out_size, void* d_ws, size_t ws_size,
                              hipStream_t stream) {
    const float* X = (const float*)d_in[0];
    float* out = (float*)d_out;

    // total quads = 12 planes * 512 rows * 128 quads/row = 786432 threads
    const int total = NPLANES * HH * (WW / 4);
    const int block = 256;
    const int grid = total / block;  // 3072
    gauss_mask_kernel<<<grid, block, 0, stream>>>(X, out);
}